// Round 7
// baseline (201.491 us; speedup 1.0000x reference)
//
#include <hip/hip_runtime.h>
#include <hip/hip_bf16.h>

#define N_NODES 50000
#define N_EDGES 800000
#define NBINS 782        // ceil(50000/64): bin = 64 consecutive dst nodes = one layer block
#define BCAP 1408        // per-bin capacity: Binomial(800k, 64/50k) = 1024 +/- 32; +12 sigma
#define EBLK 98          // edge-binning blocks
#define EPB 8192         // edges per edge-block (98*8192 >= 800k)

typedef __attribute__((ext_vector_type(8))) short short8;
typedef __attribute__((ext_vector_type(4))) float floatx4;

__device__ __forceinline__ float b2f(unsigned short h) {
    union { unsigned int u; float f; } v; v.u = ((unsigned int)h) << 16; return v.f;
}
__device__ __forceinline__ unsigned short f2b(float f) {
    union { float f; unsigned int u; } v; v.f = f;
    unsigned int r = v.u + 0x7fffu + ((v.u >> 16) & 1u);
    return (unsigned short)(r >> 16);
}
// int8 quant: q = round(16*v) clamped; dequant *1/16 (power-of-2, exact).
__device__ __forceinline__ int f2q(float f) {
    int q = __float2int_rn(f * 16.0f);
    return min(max(q, -127), 127);
}

// ---------------- prep: edge two-level binning + weight swizzle + x convert ----------------
__global__ __launch_bounds__(512) void prep_conv_rs(
                             const float* __restrict__ x, unsigned short* __restrict__ xb,
                             unsigned int* __restrict__ x8,
                             const float* __restrict__ Ws1, const float* __restrict__ Wn1,
                             const float* __restrict__ Ws2, const float* __restrict__ Wn2,
                             const float* __restrict__ Ws3, const float* __restrict__ Wn3,
                             unsigned short* __restrict__ wsw,
                             const int* __restrict__ src, const int* __restrict__ dst,
                             int* __restrict__ bincnt, unsigned int* __restrict__ binbuf) {
    __shared__ unsigned int led[EPB];
    __shared__ int hist[NBINS], gbase[NBINS];
    int b = blockIdx.x;
    int tid = threadIdx.x;

    if (b < EBLK) {
        int e0 = b * EPB;
        int nE = min(EPB, N_EDGES - e0);
        for (int i = tid; i < nE; i += 512)
            led[i] = ((unsigned int)dst[e0 + i] << 16) | (unsigned int)src[e0 + i];  // both < 65536
        for (int i = tid; i < NBINS; i += 512) hist[i] = 0;
        __syncthreads();
        for (int i = tid; i < nE; i += 512) atomicAdd(&hist[led[i] >> 22], 1);   // bin = dst>>6
        __syncthreads();
        for (int i = tid; i < NBINS; i += 512) {
            int cv = hist[i];
            gbase[i] = (cv > 0) ? atomicAdd(&bincnt[i << 4], cv) : 0;
            hist[i] = 0;                                   // reuse as local cursor
        }
        __syncthreads();
        for (int i = tid; i < nE; i += 512) {
            unsigned int u = led[i];
            int bin = u >> 22;
            int r = atomicAdd(&hist[bin], 1);
            int pos = gbase[bin] + r;
            if (pos < BCAP)
                binbuf[(size_t)bin * BCAP + pos] = (u & 0xffffu) | (((u >> 16) & 63u) << 16);
        }
        return;
    }
    if (b < EBLK + 3125) {
        int i = (b - EBLK) * 512 + tid;               // float4 index, [0, 1.6M)
        if (i < N_NODES * 32) {
            floatx4 f = ((const floatx4*)x)[i];
            uint2 o;
            o.x = ((unsigned int)f2b(f.y) << 16) | f2b(f.x);
            o.y = ((unsigned int)f2b(f.w) << 16) | f2b(f.z);
            ((uint2*)xb)[i] = o;
            unsigned int pk = ((unsigned int)(f2q(f.x) & 0xff))
                            | ((unsigned int)(f2q(f.y) & 0xff) << 8)
                            | ((unsigned int)(f2q(f.z) & 0xff) << 16)
                            | ((unsigned int)(f2q(f.w) & 0xff) << 24);
            x8[i] = pk;
        }
        return;
    }
    int t = (b - EBLK - 3125) * 512 + tid;            // weight swizzle, [0, 81920)
    if (t >= 81920) return;
    const float* W; int NC, l, base;
    if (t < 65536) {
        int mi = t >> 14; l = t & 16383; base = mi << 14; NC = 128;
        W = (mi == 0) ? Ws1 : (mi == 1) ? Wn1 : (mi == 2) ? Ws2 : Wn2;
    } else {
        int u = t - 65536; int mi = u >> 13; l = u & 8191; base = 65536 + (mi << 13); NC = 64;
        W = (mi == 0) ? Ws3 : Wn3;
    }
    int j = l & 7, lane = (l >> 3) & 63, kk = (l >> 9) & 3, c = l >> 11;
    int k = kk * 32 + ((lane >> 4) << 3) + j;
    int n = (c << 4) + (lane & 15);
    wsw[base + l] = f2b(W[k * NC + n]);
}

// int8 accumulate: 8 bytes (uint2) -> 8 int sums, exact
#define ACC8I(q)                                  \
    a[0] += (int)(signed char)((q).x);            \
    a[1] += (int)(signed char)((q).x >> 8);       \
    a[2] += (int)(signed char)((q).x >> 16);      \
    a[3] += (int)(signed char)((q).x >> 24);      \
    a[4] += (int)(signed char)((q).y);            \
    a[5] += (int)(signed char)((q).y >> 8);       \
    a[6] += (int)(signed char)((q).y >> 16);      \
    a[7] += (int)(signed char)((q).y >> 24);

// int8 accumulate: 16 bytes (uint4) -> 16 int sums, exact
#define ACC16I(q)                                  \
    a[0]  += (int)(signed char)((q).x);            \
    a[1]  += (int)(signed char)((q).x >> 8);       \
    a[2]  += (int)(signed char)((q).x >> 16);      \
    a[3]  += (int)(signed char)((q).x >> 24);      \
    a[4]  += (int)(signed char)((q).y);            \
    a[5]  += (int)(signed char)((q).y >> 8);       \
    a[6]  += (int)(signed char)((q).y >> 16);      \
    a[7]  += (int)(signed char)((q).y >> 24);      \
    a[8]  += (int)(signed char)((q).z);            \
    a[9]  += (int)(signed char)((q).z >> 8);       \
    a[10] += (int)(signed char)((q).z >> 16);      \
    a[11] += (int)(signed char)((q).z >> 24);      \
    a[12] += (int)(signed char)((q).w);            \
    a[13] += (int)(signed char)((q).w >> 8);       \
    a[14] += (int)(signed char)((q).w >> 16);      \
    a[15] += (int)(signed char)((q).w >> 24);

// split layer gather: SUB-list (stride-2 ep), int8 rows of 128B, 8 lanes x 16B/row.
// 16 lanes/node (2 subgroups of 8): halves the serial burst chain per node and the
// max-of-nodes imbalance inside a wave; integer partials combined via shfl_xor(8).
#define GATHER16I_S(P)                                                          \
    {                                                                           \
    int j = 0;                                                                  \
    for (; j + 8 <= ns; j += 8) {                                               \
        int s0 = (int)ep[(j+0)*2], s1 = (int)ep[(j+1)*2], s2 = (int)ep[(j+2)*2], s3 = (int)ep[(j+3)*2]; \
        int s4 = (int)ep[(j+4)*2], s5 = (int)ep[(j+5)*2], s6 = (int)ep[(j+6)*2], s7 = (int)ep[(j+7)*2]; \
        uint4 q0 = *(const uint4*)((P) + (size_t)s0 * 128 + c * 16);            \
        uint4 q1 = *(const uint4*)((P) + (size_t)s1 * 128 + c * 16);            \
        uint4 q2 = *(const uint4*)((P) + (size_t)s2 * 128 + c * 16);            \
        uint4 q3 = *(const uint4*)((P) + (size_t)s3 * 128 + c * 16);            \
        uint4 q4 = *(const uint4*)((P) + (size_t)s4 * 128 + c * 16);            \
        uint4 q5 = *(const uint4*)((P) + (size_t)s5 * 128 + c * 16);            \
        uint4 q6 = *(const uint4*)((P) + (size_t)s6 * 128 + c * 16);            \
        uint4 q7 = *(const uint4*)((P) + (size_t)s7 * 128 + c * 16);            \
        ACC16I(q0); ACC16I(q1); ACC16I(q2); ACC16I(q3);                         \
        ACC16I(q4); ACC16I(q5); ACC16I(q6); ACC16I(q7);                         \
    }                                                                           \
    if (j < ns) {                                                               \
        int nm = ns - 1;                                                        \
        int s0 = (int)ep[j*2],                 s1 = (int)ep[min(j + 1, nm)*2],  \
            s2 = (int)ep[min(j + 2, nm)*2],    s3 = (int)ep[min(j + 3, nm)*2],  \
            s4 = (int)ep[min(j + 4, nm)*2],    s5 = (int)ep[min(j + 5, nm)*2],  \
            s6 = (int)ep[min(j + 6, nm)*2],    s7 = (int)ep[min(j + 7, nm)*2];  \
        uint4 q0 = *(const uint4*)((P) + (size_t)s0 * 128 + c * 16);            \
        uint4 q1 = *(const uint4*)((P) + (size_t)s1 * 128 + c * 16);            \
        uint4 q2 = *(const uint4*)((P) + (size_t)s2 * 128 + c * 16);            \
        uint4 q3 = *(const uint4*)((P) + (size_t)s3 * 128 + c * 16);            \
        uint4 q4 = *(const uint4*)((P) + (size_t)s4 * 128 + c * 16);            \
        uint4 q5 = *(const uint4*)((P) + (size_t)s5 * 128 + c * 16);            \
        uint4 q6 = *(const uint4*)((P) + (size_t)s6 * 128 + c * 16);            \
        uint4 q7 = *(const uint4*)((P) + (size_t)s7 * 128 + c * 16);            \
        ACC16I(q0);                                                             \
        if (j + 1 < ns) { ACC16I(q1); }                                         \
        if (j + 2 < ns) { ACC16I(q2); }                                         \
        if (j + 3 < ns) { ACC16I(q3); }                                         \
        if (j + 4 < ns) { ACC16I(q4); }                                         \
        if (j + 5 < ns) { ACC16I(q5); }                                         \
        if (j + 6 < ns) { ACC16I(q6); }                                         \
        if (j + 7 < ns) { ACC16I(q7); }                                         \
    }                                                                           \
    }

// split final gather: SUB-list, int8 t3 rows of 64B = one line/edge, 8 lanes x 8B
#define GATHER8I64_S(P)                                                         \
    {                                                                           \
    int j = 0;                                                                  \
    for (; j + 8 <= ns; j += 8) {                                               \
        int s0 = (int)ep[(j+0)*2], s1 = (int)ep[(j+1)*2], s2 = (int)ep[(j+2)*2], s3 = (int)ep[(j+3)*2]; \
        int s4 = (int)ep[(j+4)*2], s5 = (int)ep[(j+5)*2], s6 = (int)ep[(j+6)*2], s7 = (int)ep[(j+7)*2]; \
        uint2 q0 = *(const uint2*)((P) + (size_t)s0 * 64 + c * 8);              \
        uint2 q1 = *(const uint2*)((P) + (size_t)s1 * 64 + c * 8);              \
        uint2 q2 = *(const uint2*)((P) + (size_t)s2 * 64 + c * 8);              \
        uint2 q3 = *(const uint2*)((P) + (size_t)s3 * 64 + c * 8);              \
        uint2 q4 = *(const uint2*)((P) + (size_t)s4 * 64 + c * 8);              \
        uint2 q5 = *(const uint2*)((P) + (size_t)s5 * 64 + c * 8);              \
        uint2 q6 = *(const uint2*)((P) + (size_t)s6 * 64 + c * 8);              \
        uint2 q7 = *(const uint2*)((P) + (size_t)s7 * 64 + c * 8);              \
        ACC8I(q0); ACC8I(q1); ACC8I(q2); ACC8I(q3); ACC8I(q4); ACC8I(q5); ACC8I(q6); ACC8I(q7); \
    }                                                                           \
    if (j < ns) {                                                               \
        int nm = ns - 1;                                                        \
        int s0 = (int)ep[j*2],                 s1 = (int)ep[min(j + 1, nm)*2],  \
            s2 = (int)ep[min(j + 2, nm)*2],    s3 = (int)ep[min(j + 3, nm)*2],  \
            s4 = (int)ep[min(j + 4, nm)*2],    s5 = (int)ep[min(j + 5, nm)*2],  \
            s6 = (int)ep[min(j + 6, nm)*2],    s7 = (int)ep[min(j + 7, nm)*2];  \
        uint2 q0 = *(const uint2*)((P) + (size_t)s0 * 64 + c * 8);              \
        uint2 q1 = *(const uint2*)((P) + (size_t)s1 * 64 + c * 8);              \
        uint2 q2 = *(const uint2*)((P) + (size_t)s2 * 64 + c * 8);              \
        uint2 q3 = *(const uint2*)((P) + (size_t)s3 * 64 + c * 8);              \
        uint2 q4 = *(const uint2*)((P) + (size_t)s4 * 64 + c * 8);              \
        uint2 q5 = *(const uint2*)((P) + (size_t)s5 * 64 + c * 8);              \
        uint2 q6 = *(const uint2*)((P) + (size_t)s6 * 64 + c * 8);              \
        uint2 q7 = *(const uint2*)((P) + (size_t)s7 * 64 + c * 8);              \
        ACC8I(q0);                                                              \
        if (j + 1 < ns) { ACC8I(q1); }                                          \
        if (j + 2 < ns) { ACC8I(q2); }                                          \
        if (j + 3 < ns) { ACC8I(q3); }                                          \
        if (j + 4 < ns) { ACC8I(q4); }                                          \
        if (j + 5 < ns) { ACC8I(q5); }                                          \
        if (j + 6 < ns) { ACC8I(q6); }                                          \
        if (j + 7 < ns) { ACC8I(q7); }                                          \
    }                                                                           \
    }

// ---------------- fused layer: [BUILD] LDS CSR (+spill) | [!BUILD] load CSR;
// split int8 gather means -> LDS; MFMA tile; [FUSE] epilogue dual-GEMM vs Ws3/Wn3.
template<bool BUILD, bool FUSE>
__global__ __launch_bounds__(512) void layer128_fused(
                               const unsigned short* __restrict__ X,      // bf16 rows (self GEMM A)
                               const unsigned char* __restrict__ X8,      // int8 rows (gather)
                               const unsigned int* __restrict__ binbuf,
                               const int* __restrict__ bincnt,
                               unsigned short* __restrict__ ecsr_g,
                               unsigned int* __restrict__ meta_g,
                               const unsigned short* __restrict__ Wsw1,   // self
                               const unsigned short* __restrict__ Wsw2,   // neigh
                               const float* __restrict__ bias,
                               unsigned short* __restrict__ out,          // h bf16
                               signed char* __restrict__ out8,            // h int8 (next gather)
                               const unsigned short* __restrict__ WswN3,
                               const unsigned short* __restrict__ WswS3,
                               const float* __restrict__ b3,
                               signed char* __restrict__ t3q,             // int8 (final gather)
                               unsigned short* __restrict__ outself,      // bf16
                               int nrows) {
    __shared__ __align__(16) unsigned short lds[64 * 136];   // 64 rows x 272 B
    __shared__ __align__(16) unsigned short ecsr[BCAP];
    __shared__ int lcnt[64], loff[64], lbkt[256];
    int bb = blockIdx.x;
    int base = bb * 64;
    int tid = threadIdx.x;

    // ---- phase 0: CSR (counting sort; sub-bucket order irrelevant for split gather) ----
    if (BUILD) {
        int ec = bincnt[bb << 4]; if (ec > BCAP) ec = BCAP;
        if (tid < 256) lbkt[tid] = 0;
        __syncthreads();
        const unsigned int* bp = binbuf + (size_t)bb * BCAP;
        for (int i = tid; i < ec; i += 512) {
            unsigned int u = bp[i];
            atomicAdd(&lbkt[(((u >> 16) & 63u) << 2) | ((u & 0xffffu) >> 14)], 1);
        }
        __syncthreads();
        if (tid < 64) {
            int c0 = lbkt[tid * 4], c1 = lbkt[tid * 4 + 1], c2 = lbkt[tid * 4 + 2], c3 = lbkt[tid * 4 + 3];
            int v = c0 + c1 + c2 + c3, xs = v;
            for (int o = 1; o < 64; o <<= 1) {
                int tpv = __shfl_up(xs, o, 64);
                if (tid >= o) xs += tpv;
            }
            int nb = xs - v;
            loff[tid] = nb; lcnt[tid] = v;
            lbkt[tid * 4] = nb;                 // reuse as sub-bucket cursors
            lbkt[tid * 4 + 1] = nb + c0;
            lbkt[tid * 4 + 2] = nb + c0 + c1;
            lbkt[tid * 4 + 3] = nb + c0 + c1 + c2;
        }
        __syncthreads();
        for (int i = tid; i < ec; i += 512) {
            unsigned int u = bp[i];
            int r = atomicAdd(&lbkt[(((u >> 16) & 63u) << 2) | ((u & 0xffffu) >> 14)], 1);
            ecsr[r] = (unsigned short)(u & 0xffffu);
        }
        __syncthreads();
        int nv4 = (ec * 2 + 15) >> 4;
        uint4* dq = (uint4*)(ecsr_g + (size_t)bb * BCAP);
        const uint4* sq = (const uint4*)ecsr;
        for (int i = tid; i < nv4; i += 512) dq[i] = sq[i];
        if (tid < 64) meta_g[bb * 64 + tid] = ((unsigned int)loff[tid] << 16) | (unsigned int)lcnt[tid];
    } else {
        const uint4* sq = (const uint4*)(ecsr_g + (size_t)bb * BCAP);
        uint4* dq = (uint4*)ecsr;
        for (int i = tid; i < (BCAP * 2) / 16; i += 512) dq[i] = sq[i];
        __syncthreads();
    }

    int w = tid >> 6;
    int lane = tid & 63;
    int g2 = lane >> 4;            // 4 nodes per wave
    int sub = (lane >> 3) & 1;     // edge-list half (even/odd)
    int c = lane & 7;              // 16B chunk of 128B row

    // ---- phase 1: split int8 gather: 16 lanes/node, 2 passes over 8 node-quads ----
    for (int p = 0; p < 2; ++p) {
        int nl = w * 8 + p * 4 + g2;
        int node = base + nl;
        if (node < nrows) {
            int n, off;
            if (BUILD) { n = lcnt[nl]; off = loff[nl]; }
            else { unsigned int mg = meta_g[bb * 64 + nl]; n = (int)(mg & 0xffffu); off = (int)(mg >> 16); }
            const unsigned short* ep = ecsr + off + sub;
            int ns = (n - sub + 1) >> 1;          // sub0: ceil(n/2), sub1: floor(n/2)
            int a[16];
#pragma unroll
            for (int i = 0; i < 16; ++i) a[i] = 0;
            if (ns > 0) { GATHER16I_S(X8) }
#pragma unroll
            for (int i = 0; i < 16; ++i) a[i] += __shfl_xor(a[i], 8, 64);
            float sc = 0.0625f / fmaxf((float)n, 1.0f);   // dequant 1/16 folded into mean
            int b0 = sub * 8;                     // each sub writes its 16B half
            uint4 o;
            o.x = ((unsigned int)f2b((float)a[b0+1] * sc) << 16) | f2b((float)a[b0+0] * sc);
            o.y = ((unsigned int)f2b((float)a[b0+3] * sc) << 16) | f2b((float)a[b0+2] * sc);
            o.z = ((unsigned int)f2b((float)a[b0+5] * sc) << 16) | f2b((float)a[b0+4] * sc);
            o.w = ((unsigned int)f2b((float)a[b0+7] * sc) << 16) | f2b((float)a[b0+6] * sc);
            *(uint4*)(&lds[nl * 136 + c * 16 + b0]) = o;
        }
    }
    __syncthreads();

    // ---- phase 2: gemm. wave w: rows (w&3)*16, cols (w>>2)*64 of 128 ----
    int wq = w & 3, ch = w >> 2;
    int r0 = base + wq * 16;
    int m = lane & 15, quad = lane >> 4;
    int rowc = min(r0 + m, nrows - 1);       // clamp: keep all waves alive for FUSE barriers

    floatx4 acc[4];
#pragma unroll
    for (int cc = 0; cc < 4; ++cc) acc[cc] = {0.f, 0.f, 0.f, 0.f};

#pragma unroll
    for (int kk = 0; kk < 4; ++kk) {
        short8 a1 = *(const short8*)(X + (size_t)rowc * 128 + kk * 32 + quad * 8);
        short8 a2 = *(const short8*)(&lds[(wq * 16 + m) * 136 + (kk * 4 + quad) * 8]);
#pragma unroll
        for (int cc = 0; cc < 4; ++cc) {
            int col = ch * 4 + cc;
            short8 b1 = *(const short8*)(Wsw1 + (((col * 4 + kk) * 64 + lane) << 3));
            acc[cc] = __builtin_amdgcn_mfma_f32_16x16x32_bf16(a1, b1, acc[cc], 0, 0, 0);
            short8 b2 = *(const short8*)(Wsw2 + (((col * 4 + kk) * 64 + lane) << 3));
            acc[cc] = __builtin_amdgcn_mfma_f32_16x16x32_bf16(a2, b2, acc[cc], 0, 0, 0);
        }
    }

    if (!FUSE) {
        // epilogue: h = relu(acc + bias) -> bf16 global + int8 global (next layer's gather)
#pragma unroll
        for (int r = 0; r < 4; ++r) {
            int orow = r0 + quad * 4 + r;
            if (orow < nrows) {
#pragma unroll
                for (int cc = 0; cc < 4; ++cc) {
                    int ocol = (ch * 4 + cc) * 16 + m;
                    float v = fmaxf(acc[cc][r] + bias[ocol], 0.f);
                    out[(size_t)orow * 128 + ocol] = f2b(v);
                    out8[(size_t)orow * 128 + ocol] = (signed char)min(__float2int_rn(v * 16.0f), 127);
                }
            }
        }
        return;
    }

    // ---- FUSE: h2 tile (bf16) -> LDS, then layer-3 dual GEMM ----
    __syncthreads();   // everyone done reading lds means
#pragma unroll
    for (int r = 0; r < 4; ++r) {
        int lrow = wq * 16 + quad * 4 + r;
#pragma unroll
        for (int cc = 0; cc < 4; ++cc) {
            int ocol = (ch * 4 + cc) * 16 + m;
            float v = fmaxf(acc[cc][r] + bias[ocol], 0.f);
            lds[lrow * 136 + ocol] = f2b(v);
        }
    }
    __syncthreads();

    // dual GEMM: t3 = h2 @ Wn3 (-> int8 for 1-line final gather), outself = h2 @ Ws3 + b3 (bf16)
    floatx4 accN[2], accS[2];
#pragma unroll
    for (int cc = 0; cc < 2; ++cc) { accN[cc] = {0.f, 0.f, 0.f, 0.f}; accS[cc] = {0.f, 0.f, 0.f, 0.f}; }
#pragma unroll
    for (int kk = 0; kk < 4; ++kk) {
        short8 a1 = *(const short8*)(&lds[(wq * 16 + m) * 136 + (kk * 4 + quad) * 8]);
#pragma unroll
        for (int cc = 0; cc < 2; ++cc) {
            int col = ch * 2 + cc;
            short8 bn = *(const short8*)(WswN3 + (((col * 4 + kk) * 64 + lane) << 3));
            accN[cc] = __builtin_amdgcn_mfma_f32_16x16x32_bf16(a1, bn, accN[cc], 0, 0, 0);
            short8 bs = *(const short8*)(WswS3 + (((col * 4 + kk) * 64 + lane) << 3));
            accS[cc] = __builtin_amdgcn_mfma_f32_16x16x32_bf16(a1, bs, accS[cc], 0, 0, 0);
        }
    }
#pragma unroll
    for (int r = 0; r < 4; ++r) {
        int orow = r0 + quad * 4 + r;
        if (orow < nrows) {
#pragma unroll
            for (int cc = 0; cc < 2; ++cc) {
                int ocol = (ch * 2 + cc) * 16 + m;
                t3q[(size_t)orow * 64 + ocol] = (signed char)f2q(accN[cc][r]);
                outself[(size_t)orow * 64 + ocol] = f2b(accS[cc][r] + b3[ocol]);
            }
        }
    }
}

// ---------------- gather64_final: block = bin; load CSR; split gather (16 lanes/node);
// out = out_self(bf16) + mean(t3q int8 rows) -> fp32 ----------------
__global__ __launch_bounds__(512) void gather64_final(
                               const unsigned char* __restrict__ t3q,
                               const unsigned short* __restrict__ ecsr_g,
                               const unsigned int* __restrict__ meta_g,
                               const unsigned short* __restrict__ outself, float* __restrict__ out) {
    __shared__ __align__(16) unsigned short ecsr[BCAP];
    int bb = blockIdx.x;
    int tid = threadIdx.x;

    const uint4* sq = (const uint4*)(ecsr_g + (size_t)bb * BCAP);
    uint4* dq = (uint4*)ecsr;
    for (int i = tid; i < (BCAP * 2) / 16; i += 512) dq[i] = sq[i];
    __syncthreads();

    int w = tid >> 6;
    int lane = tid & 63;
    int g2 = lane >> 4, sub = (lane >> 3) & 1, c = lane & 7;
    for (int p = 0; p < 2; ++p) {
        int nl = w * 8 + p * 4 + g2;
        int node = bb * 64 + nl;
        if (node >= N_NODES) continue;
        unsigned int mg = meta_g[bb * 64 + nl];
        int n = (int)(mg & 0xffffu), off = (int)(mg >> 16);
        const unsigned short* ep = ecsr + off + sub;
        int ns = (n - sub + 1) >> 1;
        int a[8];
#pragma unroll
        for (int i = 0; i < 8; ++i) a[i] = 0;
        if (ns > 0) { GATHER8I64_S(t3q) }
#pragma unroll
        for (int i = 0; i < 8; ++i) a[i] += __shfl_xor(a[i], 8, 64);
        float sc = 0.0625f / fmaxf((float)n, 1.0f);
        int b0 = sub * 4;                       // each sub writes its 4-float half
        const unsigned short* ip = outself + (size_t)node * 64 + c * 8 + b0;
        float* op = out + (size_t)node * 64 + c * 8 + b0;
        uint2 iv = *(const uint2*)ip;
        floatx4 o = {b2f((unsigned short)(iv.x & 0xffffu)) + (float)a[b0 + 0] * sc,
                     b2f((unsigned short)(iv.x >> 16))     + (float)a[b0 + 1] * sc,
                     b2f((unsigned short)(iv.y & 0xffffu)) + (float)a[b0 + 2] * sc,
                     b2f((unsigned short)(iv.y >> 16))     + (float)a[b0 + 3] * sc};
        *(floatx4*)op = o;
    }
}

extern "C" void kernel_launch(void* const* d_in, const int* in_sizes, int n_in,
                              void* d_out, int out_size, void* d_ws, size_t ws_size,
                              hipStream_t stream) {
    const float* x   = (const float*)d_in[0];
    const int* src   = (const int*)d_in[1];
    const int* dst   = (const int*)d_in[2];
    const float* Ws1 = (const float*)d_in[3];
    const float* b1  = (const float*)d_in[4];
    const float* Wn1 = (const float*)d_in[5];
    const float* Ws2 = (const float*)d_in[6];
    const float* b2  = (const float*)d_in[7];
    const float* Wn2 = (const float*)d_in[8];
    const float* Ws3 = (const float*)d_in[9];
    const float* b3  = (const float*)d_in[10];
    const float* Wn3 = (const float*)d_in[11];

    char* ws = (char*)d_ws;
    int* bincnt            = (int*)(ws + 0);                   //     50,048 B
    unsigned int* x8       = (unsigned int*)(ws + 50048);      //  6,400,000 B (x int8)
    signed char* h1q       = (signed char*)(ws + 6450048);     //  6,400,000 B (h1 int8)
    unsigned short* wsw    = (unsigned short*)(ws + 12850048); //    163,840 B
    unsigned int* binbuf   = (unsigned int*)(ws + 13013888);   //  4,404,224 B
    unsigned short* ecsr_g = (unsigned short*)(ws + 17418112); //  2,202,112 B
    unsigned int* meta_g   = (unsigned int*)(ws + 19620224);   //    200,192 B
    unsigned short* xb     = (unsigned short*)(ws + 19820416); // 12,800,000 B (x bf16)
    unsigned short* h1     = (unsigned short*)(ws + 32620416); // 12,800,000 B
    // L2-FUSE outputs alias xb (dead after layer-1). r2 lesson: NEVER alias h1 here --
    // layer-2's gather still reads h1 from other blocks in the same dispatch.
    signed char* t3q        = (signed char*)(ws + 19820416);    // 3,200,000 B (int8 50k x 64)
    unsigned short* outself = (unsigned short*)(ws + 26220416); // 6,400,000 B (bf16 50k x 64)

    unsigned short* sw_s1 = wsw + 0;
    unsigned short* sw_n1 = wsw + 16384;
    unsigned short* sw_s2 = wsw + 32768;
    unsigned short* sw_n2 = wsw + 49152;
    unsigned short* sw_s3 = wsw + 65536;
    unsigned short* sw_n3 = wsw + 73728;

    hipMemsetAsync(bincnt, 0, 50048, stream);
    prep_conv_rs<<<EBLK + 3125 + 160, 512, 0, stream>>>(
        x, xb, x8, Ws1, Wn1, Ws2, Wn2, Ws3, Wn3, wsw, src, dst, bincnt, binbuf);

    // ---- layer 1 (builds+spills CSR): h1 = relu(x@Ws1 + b1 + mean_agg(x8)@Wn1) ----
    layer128_fused<true, false><<<NBINS, 512, 0, stream>>>(
        xb, (const unsigned char*)x8, binbuf, bincnt, ecsr_g, meta_g, sw_s1, sw_n1, b1, h1, h1q,
        nullptr, nullptr, nullptr, nullptr, nullptr, N_NODES);

    // ---- layer 2 + fused layer-3 GEMMs: h2 = relu(...); t3q = q8(h2@Wn3); outself = h2@Ws3+b3 ----
    layer128_fused<false, true><<<NBINS, 512, 0, stream>>>(
        h1, (const unsigned char*)h1q, binbuf, bincnt, ecsr_g, meta_g, sw_s2, sw_n2, b2, nullptr, nullptr,
        sw_n3, sw_s3, b3, t3q, outself, N_NODES);

    // ---- final: out = outself + mean_agg(t3q) ----
    gather64_final<<<NBINS, 512, 0, stream>>>((const unsigned char*)t3q, ecsr_g, meta_g, outself, (float*)d_out);
}

// Round 8
// 185.317 us; speedup vs baseline: 1.0873x; 1.0873x over previous
//
#include <hip/hip_runtime.h>
#include <hip/hip_bf16.h>

#define N_NODES 50000
#define N_EDGES 800000
#define NBINS 782        // ceil(50000/64): bin = 64 consecutive dst nodes = one layer block
#define BCAP 1408        // per-bin capacity: Binomial(800k, 64/50k) = 1024 +/- 32; +12 sigma
#define EBLK 98          // edge-binning blocks
#define EPB 8192         // edges per edge-block (98*8192 >= 800k)

typedef __attribute__((ext_vector_type(8))) short short8;
typedef __attribute__((ext_vector_type(4))) float floatx4;

__device__ __forceinline__ float b2f(unsigned short h) {
    union { unsigned int u; float f; } v; v.u = ((unsigned int)h) << 16; return v.f;
}
__device__ __forceinline__ unsigned short f2b(float f) {
    union { float f; unsigned int u; } v; v.f = f;
    unsigned int r = v.u + 0x7fffu + ((v.u >> 16) & 1u);
    return (unsigned short)(r >> 16);
}
// int8 quant: q = round(16*v) clamped; dequant *1/16 (power-of-2, exact).
__device__ __forceinline__ int f2q(float f) {
    int q = __float2int_rn(f * 16.0f);
    return min(max(q, -127), 127);
}

// ---------------- prep: edge two-level binning + weight swizzle + x convert ----------------
__global__ __launch_bounds__(512) void prep_conv_rs(
                             const float* __restrict__ x, unsigned short* __restrict__ xb,
                             unsigned int* __restrict__ x8,
                             const float* __restrict__ Ws1, const float* __restrict__ Wn1,
                             const float* __restrict__ Ws2, const float* __restrict__ Wn2,
                             const float* __restrict__ Ws3, const float* __restrict__ Wn3,
                             unsigned short* __restrict__ wsw,
                             const int* __restrict__ src, const int* __restrict__ dst,
                             int* __restrict__ bincnt, unsigned int* __restrict__ binbuf) {
    __shared__ unsigned int led[EPB];
    __shared__ int hist[NBINS], gbase[NBINS];
    int b = blockIdx.x;
    int tid = threadIdx.x;

    if (b < EBLK) {
        int e0 = b * EPB;
        int nE = min(EPB, N_EDGES - e0);
        for (int i = tid; i < nE; i += 512)
            led[i] = ((unsigned int)dst[e0 + i] << 16) | (unsigned int)src[e0 + i];  // both < 65536
        for (int i = tid; i < NBINS; i += 512) hist[i] = 0;
        __syncthreads();
        for (int i = tid; i < nE; i += 512) atomicAdd(&hist[led[i] >> 22], 1);   // bin = dst>>6
        __syncthreads();
        for (int i = tid; i < NBINS; i += 512) {
            int cv = hist[i];
            gbase[i] = (cv > 0) ? atomicAdd(&bincnt[i << 4], cv) : 0;
            hist[i] = 0;                                   // reuse as local cursor
        }
        __syncthreads();
        for (int i = tid; i < nE; i += 512) {
            unsigned int u = led[i];
            int bin = u >> 22;
            int r = atomicAdd(&hist[bin], 1);
            int pos = gbase[bin] + r;
            if (pos < BCAP)
                binbuf[(size_t)bin * BCAP + pos] = (u & 0xffffu) | (((u >> 16) & 63u) << 16);
        }
        return;
    }
    if (b < EBLK + 3125) {
        int i = (b - EBLK) * 512 + tid;               // float4 index, [0, 1.6M)
        if (i < N_NODES * 32) {
            floatx4 f = ((const floatx4*)x)[i];
            uint2 o;
            o.x = ((unsigned int)f2b(f.y) << 16) | f2b(f.x);
            o.y = ((unsigned int)f2b(f.w) << 16) | f2b(f.z);
            ((uint2*)xb)[i] = o;
            unsigned int pk = ((unsigned int)(f2q(f.x) & 0xff))
                            | ((unsigned int)(f2q(f.y) & 0xff) << 8)
                            | ((unsigned int)(f2q(f.z) & 0xff) << 16)
                            | ((unsigned int)(f2q(f.w) & 0xff) << 24);
            x8[i] = pk;
        }
        return;
    }
    int t = (b - EBLK - 3125) * 512 + tid;            // weight swizzle, [0, 81920)
    if (t >= 81920) return;
    const float* W; int NC, l, base;
    if (t < 65536) {
        int mi = t >> 14; l = t & 16383; base = mi << 14; NC = 128;
        W = (mi == 0) ? Ws1 : (mi == 1) ? Wn1 : (mi == 2) ? Ws2 : Wn2;
    } else {
        int u = t - 65536; int mi = u >> 13; l = u & 8191; base = 65536 + (mi << 13); NC = 64;
        W = (mi == 0) ? Ws3 : Wn3;
    }
    int j = l & 7, lane = (l >> 3) & 63, kk = (l >> 9) & 3, c = l >> 11;
    int k = kk * 32 + ((lane >> 4) << 3) + j;
    int n = (c << 4) + (lane & 15);
    wsw[base + l] = f2b(W[k * NC + n]);
}

// int8 accumulate: 8 bytes (uint2) -> 8 int sums, exact
#define ACC8I(q)                                  \
    a[0] += (int)(signed char)((q).x);            \
    a[1] += (int)(signed char)((q).x >> 8);       \
    a[2] += (int)(signed char)((q).x >> 16);      \
    a[3] += (int)(signed char)((q).x >> 24);      \
    a[4] += (int)(signed char)((q).y);            \
    a[5] += (int)(signed char)((q).y >> 8);       \
    a[6] += (int)(signed char)((q).y >> 16);      \
    a[7] += (int)(signed char)((q).y >> 24);

// int8 accumulate: 16 bytes (uint4) -> 16 int sums, exact
#define ACC16I(q)                                  \
    a[0]  += (int)(signed char)((q).x);            \
    a[1]  += (int)(signed char)((q).x >> 8);       \
    a[2]  += (int)(signed char)((q).x >> 16);      \
    a[3]  += (int)(signed char)((q).x >> 24);      \
    a[4]  += (int)(signed char)((q).y);            \
    a[5]  += (int)(signed char)((q).y >> 8);       \
    a[6]  += (int)(signed char)((q).y >> 16);      \
    a[7]  += (int)(signed char)((q).y >> 24);      \
    a[8]  += (int)(signed char)((q).z);            \
    a[9]  += (int)(signed char)((q).z >> 8);       \
    a[10] += (int)(signed char)((q).z >> 16);      \
    a[11] += (int)(signed char)((q).z >> 24);      \
    a[12] += (int)(signed char)((q).w);            \
    a[13] += (int)(signed char)((q).w >> 8);       \
    a[14] += (int)(signed char)((q).w >> 16);      \
    a[15] += (int)(signed char)((q).w >> 24);

// layer gather: int8 rows of 128B, 8 lanes x 16B/row
#define GATHER16I(P)                                                            \
    int j = 0;                                                                  \
    for (; j + 8 <= n; j += 8) {                                                \
        int s0 = (int)ep[j],     s1 = (int)ep[j + 1], s2 = (int)ep[j + 2], s3 = (int)ep[j + 3]; \
        int s4 = (int)ep[j + 4], s5 = (int)ep[j + 5], s6 = (int)ep[j + 6], s7 = (int)ep[j + 7]; \
        uint4 q0 = *(const uint4*)((P) + (size_t)s0 * 128 + c * 16);            \
        uint4 q1 = *(const uint4*)((P) + (size_t)s1 * 128 + c * 16);            \
        uint4 q2 = *(const uint4*)((P) + (size_t)s2 * 128 + c * 16);            \
        uint4 q3 = *(const uint4*)((P) + (size_t)s3 * 128 + c * 16);            \
        uint4 q4 = *(const uint4*)((P) + (size_t)s4 * 128 + c * 16);            \
        uint4 q5 = *(const uint4*)((P) + (size_t)s5 * 128 + c * 16);            \
        uint4 q6 = *(const uint4*)((P) + (size_t)s6 * 128 + c * 16);            \
        uint4 q7 = *(const uint4*)((P) + (size_t)s7 * 128 + c * 16);            \
        ACC16I(q0); ACC16I(q1); ACC16I(q2); ACC16I(q3);                         \
        ACC16I(q4); ACC16I(q5); ACC16I(q6); ACC16I(q7);                         \
    }                                                                           \
    if (j < n) {                                                                \
        int nm = n - 1;                                                         \
        int s0 = (int)ep[j],               s1 = (int)ep[min(j + 1, nm)],        \
            s2 = (int)ep[min(j + 2, nm)],  s3 = (int)ep[min(j + 3, nm)],        \
            s4 = (int)ep[min(j + 4, nm)],  s5 = (int)ep[min(j + 5, nm)],        \
            s6 = (int)ep[min(j + 6, nm)],  s7 = (int)ep[min(j + 7, nm)];        \
        uint4 q0 = *(const uint4*)((P) + (size_t)s0 * 128 + c * 16);            \
        uint4 q1 = *(const uint4*)((P) + (size_t)s1 * 128 + c * 16);            \
        uint4 q2 = *(const uint4*)((P) + (size_t)s2 * 128 + c * 16);            \
        uint4 q3 = *(const uint4*)((P) + (size_t)s3 * 128 + c * 16);            \
        uint4 q4 = *(const uint4*)((P) + (size_t)s4 * 128 + c * 16);            \
        uint4 q5 = *(const uint4*)((P) + (size_t)s5 * 128 + c * 16);            \
        uint4 q6 = *(const uint4*)((P) + (size_t)s6 * 128 + c * 16);            \
        uint4 q7 = *(const uint4*)((P) + (size_t)s7 * 128 + c * 16);            \
        ACC16I(q0);                                                             \
        if (j + 1 < n) { ACC16I(q1); }                                          \
        if (j + 2 < n) { ACC16I(q2); }                                          \
        if (j + 3 < n) { ACC16I(q3); }                                          \
        if (j + 4 < n) { ACC16I(q4); }                                          \
        if (j + 5 < n) { ACC16I(q5); }                                          \
        if (j + 6 < n) { ACC16I(q6); }                                          \
        if (j + 7 < n) { ACC16I(q7); }                                          \
    }

// final gather: int8 t3 rows of 64B = ONE line per edge, 8 lanes x 8B
#define GATHER8I64(P)                                                           \
    int j = 0;                                                                  \
    for (; j + 8 <= n; j += 8) {                                                \
        int s0 = (int)ep[j],     s1 = (int)ep[j + 1], s2 = (int)ep[j + 2], s3 = (int)ep[j + 3]; \
        int s4 = (int)ep[j + 4], s5 = (int)ep[j + 5], s6 = (int)ep[j + 6], s7 = (int)ep[j + 7]; \
        uint2 q0 = *(const uint2*)((P) + (size_t)s0 * 64 + c * 8);              \
        uint2 q1 = *(const uint2*)((P) + (size_t)s1 * 64 + c * 8);              \
        uint2 q2 = *(const uint2*)((P) + (size_t)s2 * 64 + c * 8);              \
        uint2 q3 = *(const uint2*)((P) + (size_t)s3 * 64 + c * 8);              \
        uint2 q4 = *(const uint2*)((P) + (size_t)s4 * 64 + c * 8);              \
        uint2 q5 = *(const uint2*)((P) + (size_t)s5 * 64 + c * 8);              \
        uint2 q6 = *(const uint2*)((P) + (size_t)s6 * 64 + c * 8);              \
        uint2 q7 = *(const uint2*)((P) + (size_t)s7 * 64 + c * 8);              \
        ACC8I(q0); ACC8I(q1); ACC8I(q2); ACC8I(q3); ACC8I(q4); ACC8I(q5); ACC8I(q6); ACC8I(q7); \
    }                                                                           \
    if (j < n) {                                                                \
        int nm = n - 1;                                                         \
        int s0 = (int)ep[j],               s1 = (int)ep[min(j + 1, nm)],        \
            s2 = (int)ep[min(j + 2, nm)],  s3 = (int)ep[min(j + 3, nm)],        \
            s4 = (int)ep[min(j + 4, nm)],  s5 = (int)ep[min(j + 5, nm)],        \
            s6 = (int)ep[min(j + 6, nm)],  s7 = (int)ep[min(j + 7, nm)];        \
        uint2 q0 = *(const uint2*)((P) + (size_t)s0 * 64 + c * 8);              \
        uint2 q1 = *(const uint2*)((P) + (size_t)s1 * 64 + c * 8);              \
        uint2 q2 = *(const uint2*)((P) + (size_t)s2 * 64 + c * 8);              \
        uint2 q3 = *(const uint2*)((P) + (size_t)s3 * 64 + c * 8);              \
        uint2 q4 = *(const uint2*)((P) + (size_t)s4 * 64 + c * 8);              \
        uint2 q5 = *(const uint2*)((P) + (size_t)s5 * 64 + c * 8);              \
        uint2 q6 = *(const uint2*)((P) + (size_t)s6 * 64 + c * 8);              \
        uint2 q7 = *(const uint2*)((P) + (size_t)s7 * 64 + c * 8);              \
        ACC8I(q0);                                                              \
        if (j + 1 < n) { ACC8I(q1); }                                           \
        if (j + 2 < n) { ACC8I(q2); }                                           \
        if (j + 3 < n) { ACC8I(q3); }                                           \
        if (j + 4 < n) { ACC8I(q4); }                                           \
        if (j + 5 < n) { ACC8I(q5); }                                           \
        if (j + 6 < n) { ACC8I(q6); }                                           \
        if (j + 7 < n) { ACC8I(q7); }                                           \
    }

// ---------------- fused layer: [BUILD] LDS CSR (+spill) | [!BUILD] load CSR;
// int8 gather means -> LDS; MFMA tile; [FUSE] epilogue dual-GEMM vs Ws3/Wn3.
template<bool BUILD, bool FUSE>
__global__ __launch_bounds__(512) void layer128_fused(
                               const unsigned short* __restrict__ X,      // bf16 rows (self GEMM A)
                               const unsigned char* __restrict__ X8,      // int8 rows (gather)
                               const unsigned int* __restrict__ binbuf,
                               const int* __restrict__ bincnt,
                               unsigned short* __restrict__ ecsr_g,
                               unsigned int* __restrict__ meta_g,
                               const unsigned short* __restrict__ Wsw1,   // self
                               const unsigned short* __restrict__ Wsw2,   // neigh
                               const float* __restrict__ bias,
                               unsigned short* __restrict__ out,          // h bf16
                               signed char* __restrict__ out8,            // h int8 (next gather)
                               const unsigned short* __restrict__ WswN3,
                               const unsigned short* __restrict__ WswS3,
                               const float* __restrict__ b3,
                               signed char* __restrict__ t3q,             // int8 (final gather)
                               unsigned short* __restrict__ outself,      // bf16
                               int nrows) {
    __shared__ __align__(16) unsigned short lds[64 * 136];   // 64 rows x 272 B
    __shared__ __align__(16) unsigned short ecsr[BCAP];
    __shared__ int lcnt[64], loff[64], lbkt[256];
    int bb = blockIdx.x;
    int base = bb * 64;
    int tid = threadIdx.x;

    // ---- phase 0: CSR (counting sort) ----
    if (BUILD) {
        int ec = bincnt[bb << 4]; if (ec > BCAP) ec = BCAP;
        if (tid < 256) lbkt[tid] = 0;
        __syncthreads();
        const unsigned int* bp = binbuf + (size_t)bb * BCAP;
        for (int i = tid; i < ec; i += 512) {
            unsigned int u = bp[i];
            atomicAdd(&lbkt[(((u >> 16) & 63u) << 2) | ((u & 0xffffu) >> 14)], 1);
        }
        __syncthreads();
        if (tid < 64) {
            int c0 = lbkt[tid * 4], c1 = lbkt[tid * 4 + 1], c2 = lbkt[tid * 4 + 2], c3 = lbkt[tid * 4 + 3];
            int v = c0 + c1 + c2 + c3, xs = v;
            for (int o = 1; o < 64; o <<= 1) {
                int tpv = __shfl_up(xs, o, 64);
                if (tid >= o) xs += tpv;
            }
            int nb = xs - v;
            loff[tid] = nb; lcnt[tid] = v;
            lbkt[tid * 4] = nb;                 // reuse as sub-bucket cursors
            lbkt[tid * 4 + 1] = nb + c0;
            lbkt[tid * 4 + 2] = nb + c0 + c1;
            lbkt[tid * 4 + 3] = nb + c0 + c1 + c2;
        }
        __syncthreads();
        for (int i = tid; i < ec; i += 512) {
            unsigned int u = bp[i];
            int r = atomicAdd(&lbkt[(((u >> 16) & 63u) << 2) | ((u & 0xffffu) >> 14)], 1);
            ecsr[r] = (unsigned short)(u & 0xffffu);
        }
        __syncthreads();
        int nv4 = (ec * 2 + 15) >> 4;
        uint4* dq = (uint4*)(ecsr_g + (size_t)bb * BCAP);
        const uint4* sq = (const uint4*)ecsr;
        for (int i = tid; i < nv4; i += 512) dq[i] = sq[i];
        if (tid < 64) meta_g[bb * 64 + tid] = ((unsigned int)loff[tid] << 16) | (unsigned int)lcnt[tid];
    } else {
        const uint4* sq = (const uint4*)(ecsr_g + (size_t)bb * BCAP);
        uint4* dq = (uint4*)ecsr;
        for (int i = tid; i < (BCAP * 2) / 16; i += 512) dq[i] = sq[i];
        __syncthreads();
    }

    int w = tid >> 6;
    int lane = tid & 63;
    int g = lane >> 3, c = lane & 7;   // 8 lanes x 16B per row

    // ---- phase 1: int8 gather: wave w node w*8+g, lane c = 16B chunk ----
    {
        int nl = w * 8 + g;
        int node = base + nl;
        if (node < nrows) {
            int n, off;
            if (BUILD) { n = lcnt[nl]; off = loff[nl]; }
            else { unsigned int mg = meta_g[bb * 64 + nl]; n = (int)(mg & 0xffffu); off = (int)(mg >> 16); }
            const unsigned short* ep = ecsr + off;
            int a[16];
#pragma unroll
            for (int i = 0; i < 16; ++i) a[i] = 0;
            GATHER16I(X8)
            float sc = 0.0625f / fmaxf((float)n, 1.0f);   // dequant 1/16 folded into mean
            uint4 o0, o1;
            o0.x = ((unsigned int)f2b((float)a[1]  * sc) << 16) | f2b((float)a[0]  * sc);
            o0.y = ((unsigned int)f2b((float)a[3]  * sc) << 16) | f2b((float)a[2]  * sc);
            o0.z = ((unsigned int)f2b((float)a[5]  * sc) << 16) | f2b((float)a[4]  * sc);
            o0.w = ((unsigned int)f2b((float)a[7]  * sc) << 16) | f2b((float)a[6]  * sc);
            o1.x = ((unsigned int)f2b((float)a[9]  * sc) << 16) | f2b((float)a[8]  * sc);
            o1.y = ((unsigned int)f2b((float)a[11] * sc) << 16) | f2b((float)a[10] * sc);
            o1.z = ((unsigned int)f2b((float)a[13] * sc) << 16) | f2b((float)a[12] * sc);
            o1.w = ((unsigned int)f2b((float)a[15] * sc) << 16) | f2b((float)a[14] * sc);
            *(uint4*)(&lds[nl * 136 + c * 16]) = o0;
            *(uint4*)(&lds[nl * 136 + c * 16 + 8]) = o1;
        }
    }
    __syncthreads();

    // ---- phase 2: gemm. wave w: rows (w&3)*16, cols (w>>2)*64 of 128 ----
    int wq = w & 3, ch = w >> 2;
    int r0 = base + wq * 16;
    int m = lane & 15, quad = lane >> 4;
    int rowc = min(r0 + m, nrows - 1);       // clamp: keep all waves alive for FUSE barriers

    floatx4 acc[4];
#pragma unroll
    for (int cc = 0; cc < 4; ++cc) acc[cc] = {0.f, 0.f, 0.f, 0.f};

#pragma unroll
    for (int kk = 0; kk < 4; ++kk) {
        short8 a1 = *(const short8*)(X + (size_t)rowc * 128 + kk * 32 + quad * 8);
        short8 a2 = *(const short8*)(&lds[(wq * 16 + m) * 136 + (kk * 4 + quad) * 8]);
#pragma unroll
        for (int cc = 0; cc < 4; ++cc) {
            int col = ch * 4 + cc;
            short8 b1 = *(const short8*)(Wsw1 + (((col * 4 + kk) * 64 + lane) << 3));
            acc[cc] = __builtin_amdgcn_mfma_f32_16x16x32_bf16(a1, b1, acc[cc], 0, 0, 0);
            short8 b2 = *(const short8*)(Wsw2 + (((col * 4 + kk) * 64 + lane) << 3));
            acc[cc] = __builtin_amdgcn_mfma_f32_16x16x32_bf16(a2, b2, acc[cc], 0, 0, 0);
        }
    }

    if (!FUSE) {
        // epilogue: h = relu(acc + bias) -> bf16 global + int8 global (next layer's gather)
#pragma unroll
        for (int r = 0; r < 4; ++r) {
            int orow = r0 + quad * 4 + r;
            if (orow < nrows) {
#pragma unroll
                for (int cc = 0; cc < 4; ++cc) {
                    int ocol = (ch * 4 + cc) * 16 + m;
                    float v = fmaxf(acc[cc][r] + bias[ocol], 0.f);
                    out[(size_t)orow * 128 + ocol] = f2b(v);
                    out8[(size_t)orow * 128 + ocol] = (signed char)min(__float2int_rn(v * 16.0f), 127);
                }
            }
        }
        return;
    }

    // ---- FUSE: h2 tile (bf16) -> LDS, then layer-3 dual GEMM ----
    __syncthreads();   // everyone done reading lds means
#pragma unroll
    for (int r = 0; r < 4; ++r) {
        int lrow = wq * 16 + quad * 4 + r;
#pragma unroll
        for (int cc = 0; cc < 4; ++cc) {
            int ocol = (ch * 4 + cc) * 16 + m;
            float v = fmaxf(acc[cc][r] + bias[ocol], 0.f);
            lds[lrow * 136 + ocol] = f2b(v);
        }
    }
    __syncthreads();

    // dual GEMM: t3 = h2 @ Wn3 (-> int8 for 1-line final gather), outself = h2 @ Ws3 + b3 (bf16)
    floatx4 accN[2], accS[2];
#pragma unroll
    for (int cc = 0; cc < 2; ++cc) { accN[cc] = {0.f, 0.f, 0.f, 0.f}; accS[cc] = {0.f, 0.f, 0.f, 0.f}; }
#pragma unroll
    for (int kk = 0; kk < 4; ++kk) {
        short8 a1 = *(const short8*)(&lds[(wq * 16 + m) * 136 + (kk * 4 + quad) * 8]);
#pragma unroll
        for (int cc = 0; cc < 2; ++cc) {
            int col = ch * 2 + cc;
            short8 bn = *(const short8*)(WswN3 + (((col * 4 + kk) * 64 + lane) << 3));
            accN[cc] = __builtin_amdgcn_mfma_f32_16x16x32_bf16(a1, bn, accN[cc], 0, 0, 0);
            short8 bs = *(const short8*)(WswS3 + (((col * 4 + kk) * 64 + lane) << 3));
            accS[cc] = __builtin_amdgcn_mfma_f32_16x16x32_bf16(a1, bs, accS[cc], 0, 0, 0);
        }
    }
#pragma unroll
    for (int r = 0; r < 4; ++r) {
        int orow = r0 + quad * 4 + r;
        if (orow < nrows) {
#pragma unroll
            for (int cc = 0; cc < 2; ++cc) {
                int ocol = (ch * 2 + cc) * 16 + m;
                t3q[(size_t)orow * 64 + ocol] = (signed char)f2q(accN[cc][r]);
                outself[(size_t)orow * 64 + ocol] = f2b(accS[cc][r] + b3[ocol]);
            }
        }
    }
}

// ---------------- gather64_final: block = bin; load CSR; 8 waves x 8 nodes;
// out = out_self(bf16) + mean(t3q int8 rows) -> fp32 ----------------
__global__ __launch_bounds__(512) void gather64_final(
                               const unsigned char* __restrict__ t3q,
                               const unsigned short* __restrict__ ecsr_g,
                               const unsigned int* __restrict__ meta_g,
                               const unsigned short* __restrict__ outself, float* __restrict__ out) {
    __shared__ __align__(16) unsigned short ecsr[BCAP];
    int bb = blockIdx.x;
    int tid = threadIdx.x;

    const uint4* sq = (const uint4*)(ecsr_g + (size_t)bb * BCAP);
    uint4* dq = (uint4*)ecsr;
    for (int i = tid; i < (BCAP * 2) / 16; i += 512) dq[i] = sq[i];
    __syncthreads();

    int w = tid >> 6;
    int lane = tid & 63;
    int g = lane >> 3, c = lane & 7;
    int nl = w * 8 + g;
    int node = bb * 64 + nl;
    if (node >= N_NODES) return;
    unsigned int mg = meta_g[bb * 64 + nl];
    int n = (int)(mg & 0xffffu), off = (int)(mg >> 16);
    const unsigned short* ep = ecsr + off;
    int a[8];
#pragma unroll
    for (int i = 0; i < 8; ++i) a[i] = 0;
    GATHER8I64(t3q)
    float sc = 0.0625f / fmaxf((float)n, 1.0f);
    const unsigned short* ip = outself + (size_t)node * 64 + c * 8;
    float* op = out + (size_t)node * 64 + c * 8;
    uint4 iv = *(const uint4*)ip;
    floatx4 o0 = {b2f((unsigned short)(iv.x & 0xffffu)) + (float)a[0] * sc,
                  b2f((unsigned short)(iv.x >> 16))     + (float)a[1] * sc,
                  b2f((unsigned short)(iv.y & 0xffffu)) + (float)a[2] * sc,
                  b2f((unsigned short)(iv.y >> 16))     + (float)a[3] * sc};
    floatx4 o1 = {b2f((unsigned short)(iv.z & 0xffffu)) + (float)a[4] * sc,
                  b2f((unsigned short)(iv.z >> 16))     + (float)a[5] * sc,
                  b2f((unsigned short)(iv.w & 0xffffu)) + (float)a[6] * sc,
                  b2f((unsigned short)(iv.w >> 16))     + (float)a[7] * sc};
    *(floatx4*)op = o0;
    *(floatx4*)(op + 4) = o1;
}

extern "C" void kernel_launch(void* const* d_in, const int* in_sizes, int n_in,
                              void* d_out, int out_size, void* d_ws, size_t ws_size,
                              hipStream_t stream) {
    const float* x   = (const float*)d_in[0];
    const int* src   = (const int*)d_in[1];
    const int* dst   = (const int*)d_in[2];
    const float* Ws1 = (const float*)d_in[3];
    const float* b1  = (const float*)d_in[4];
    const float* Wn1 = (const float*)d_in[5];
    const float* Ws2 = (const float*)d_in[6];
    const float* b2  = (const float*)d_in[7];
    const float* Wn2 = (const float*)d_in[8];
    const float* Ws3 = (const float*)d_in[9];
    const float* b3  = (const float*)d_in[10];
    const float* Wn3 = (const float*)d_in[11];

    char* ws = (char*)d_ws;
    int* bincnt            = (int*)(ws + 0);                   //     50,048 B
    unsigned int* x8       = (unsigned int*)(ws + 50048);      //  6,400,000 B (x int8)
    signed char* h1q       = (signed char*)(ws + 6450048);     //  6,400,000 B (h1 int8)
    unsigned short* wsw    = (unsigned short*)(ws + 12850048); //    163,840 B
    unsigned int* binbuf   = (unsigned int*)(ws + 13013888);   //  4,404,224 B
    unsigned short* ecsr_g = (unsigned short*)(ws + 17418112); //  2,202,112 B
    unsigned int* meta_g   = (unsigned int*)(ws + 19620224);   //    200,192 B
    unsigned short* xb     = (unsigned short*)(ws + 19820416); // 12,800,000 B (x bf16)
    unsigned short* h1     = (unsigned short*)(ws + 32620416); // 12,800,000 B
    // L2-FUSE outputs alias xb (dead after layer-1). r2 lesson: NEVER alias h1 here --
    // layer-2's gather still reads h1 from other blocks in the same dispatch.
    signed char* t3q        = (signed char*)(ws + 19820416);    // 3,200,000 B (int8 50k x 64)
    unsigned short* outself = (unsigned short*)(ws + 26220416); // 6,400,000 B (bf16 50k x 64)

    unsigned short* sw_s1 = wsw + 0;
    unsigned short* sw_n1 = wsw + 16384;
    unsigned short* sw_s2 = wsw + 32768;
    unsigned short* sw_n2 = wsw + 49152;
    unsigned short* sw_s3 = wsw + 65536;
    unsigned short* sw_n3 = wsw + 73728;

    hipMemsetAsync(bincnt, 0, 50048, stream);
    prep_conv_rs<<<EBLK + 3125 + 160, 512, 0, stream>>>(
        x, xb, x8, Ws1, Wn1, Ws2, Wn2, Ws3, Wn3, wsw, src, dst, bincnt, binbuf);

    // ---- layer 1 (builds+spills CSR): h1 = relu(x@Ws1 + b1 + mean_agg(x8)@Wn1) ----
    layer128_fused<true, false><<<NBINS, 512, 0, stream>>>(
        xb, (const unsigned char*)x8, binbuf, bincnt, ecsr_g, meta_g, sw_s1, sw_n1, b1, h1, h1q,
        nullptr, nullptr, nullptr, nullptr, nullptr, N_NODES);

    // ---- layer 2 + fused layer-3 GEMMs: h2 = relu(...); t3q = q8(h2@Wn3); outself = h2@Ws3+b3 ----
    layer128_fused<false, true><<<NBINS, 512, 0, stream>>>(
        h1, (const unsigned char*)h1q, binbuf, bincnt, ecsr_g, meta_g, sw_s2, sw_n2, b2, nullptr, nullptr,
        sw_n3, sw_s3, b3, t3q, outself, N_NODES);

    // ---- final: out = outself + mean_agg(t3q) ----
    gather64_final<<<NBINS, 512, 0, stream>>>((const unsigned char*)t3q, ecsr_g, meta_g, outself, (float*)d_out);
}